// Round 10
// baseline (1186.689 us; speedup 1.0000x reference)
//
#include <hip/hip_runtime.h>
#include <math.h>

// Dims (fixed by the problem)
#define HH   50          // hidden
#define GG   150         // 3H
#define XGS  152         // xg row stride (padded)
#define TTT  2048        // T
#define NB   64          // batch B
#define MTOT (TTT*NB)    // 131072 rows per layer
#define D0   128         // layer-0 input dim

static __device__ __forceinline__ float sigm(float x) {
    return 1.f / (1.f + __expf(-x));
}
static __device__ __forceinline__ float tanh_f(float x) {
    return 1.f - 2.f / (__expf(2.f * x) + 1.f);   // saturates correctly at +/-inf
}

static __device__ __forceinline__ void fma4(float4& a, float s, const float4& w) {
    a.x += s * w.x; a.y += s * w.y; a.z += s * w.z; a.w += s * w.w;
}

static __device__ __forceinline__ float bcast(float v, int k) {
    // wave-uniform broadcast of lane k's value (v_readlane_b32, SGPR lane idx)
    return __uint_as_float(__builtin_amdgcn_readlane(__float_as_uint(v), k));
}

// ---------------- Layer-0 input projection: Xg = X0 @ W + bi ----------------
// (proven, ~110 us)
__global__ __launch_bounds__(256) void proj0_kernel(
    const float* __restrict__ x,              // [64,2048,128] f32
    const float* __restrict__ W,              // [128,150] f32
    const float* __restrict__ bias,           // [2,150] f32 (bi = bias[0])
    float* __restrict__ xg)                   // [MTOT,XGS] f32
{
    __shared__ float xs[128][36];             // k-quarter of x, stride 36 (18.4 KB)
    __shared__ float Wp[32][32];              // k-quarter of W cols for this tile (4 KB)
    const int tid  = threadIdx.x;
    const int m0   = blockIdx.x * 128;
    const int c0   = blockIdx.y * 32;         // col-tile base: 0,32,64,96,128
    const int rowq = tid >> 3;                // 0..31
    const int colq = tid & 7;                 // 0..7

    float4 acc[4];
    #pragma unroll
    for (int j = 0; j < 4; ++j) acc[j] = make_float4(0.f, 0.f, 0.f, 0.f);

    for (int q = 0; q < 4; ++q) {             // K quarters of 32
        if (q) __syncthreads();
        for (int i = tid; i < 128 * 8; i += 256) {
            int r = i >> 3, k4 = (i & 7) * 4;
            int row = m0 + r, t = row >> 6, b = row & 63;
            *(float4*)&xs[r][k4] =
                *(const float4*)&x[((size_t)b * TTT + t) * D0 + q * 32 + k4];
        }
        for (int i = tid; i < 32 * 32; i += 256) {
            int k = i >> 5, c = i & 31, gc = c0 + c;
            Wp[k][c] = (gc < GG) ? W[(q * 32 + k) * GG + gc] : 0.f;
        }
        __syncthreads();
        const float* xr0 = xs[rowq * 4 + 0];
        const float* xr1 = xs[rowq * 4 + 1];
        const float* xr2 = xs[rowq * 4 + 2];
        const float* xr3 = xs[rowq * 4 + 3];
        for (int k = 0; k < 32; k += 4) {
            float4 w0 = *(const float4*)&Wp[k + 0][colq * 4];
            float4 w1 = *(const float4*)&Wp[k + 1][colq * 4];
            float4 w2 = *(const float4*)&Wp[k + 2][colq * 4];
            float4 w3 = *(const float4*)&Wp[k + 3][colq * 4];
            float4 x0 = *(const float4*)&xr0[k];
            float4 x1 = *(const float4*)&xr1[k];
            float4 x2 = *(const float4*)&xr2[k];
            float4 x3 = *(const float4*)&xr3[k];
            fma4(acc[0], x0.x, w0); fma4(acc[0], x0.y, w1);
            fma4(acc[0], x0.z, w2); fma4(acc[0], x0.w, w3);
            fma4(acc[1], x1.x, w0); fma4(acc[1], x1.y, w1);
            fma4(acc[1], x1.z, w2); fma4(acc[1], x1.w, w3);
            fma4(acc[2], x2.x, w0); fma4(acc[2], x2.y, w1);
            fma4(acc[2], x2.z, w2); fma4(acc[2], x2.w, w3);
            fma4(acc[3], x3.x, w0); fma4(acc[3], x3.y, w1);
            fma4(acc[3], x3.z, w2); fma4(acc[3], x3.w, w3);
        }
    }
    const int cc = c0 + colq * 4;
    if (cc <= XGS - 4) {                      // cc <= 148; cols 150/151 unread pad
        float4 bv = *(const float4*)&bias[cc];
        #pragma unroll
        for (int j = 0; j < 4; ++j) {
            float4 o;
            o.x = acc[j].x + bv.x; o.y = acc[j].y + bv.y;
            o.z = acc[j].z + bv.z; o.w = acc[j].w + bv.w;
            *(float4*)&xg[(size_t)(m0 + rowq * 4 + j) * XGS + cc] = o;
        }
    }
}

// ---------------- Layers 1..5 input projection GEMM (K=50, padded to 52) ----------------
// Round-3/5 proven (~41 us by subtraction). Register-tiled 4x4: ~4 MACs per
// v_fma -- 4.5x the instruction efficiency of the fused readlane projection
// (round-9 finding: fused projection was the VALU floor, not LDS BW).
__global__ __launch_bounds__(256) void projH_kernel(
    const float* __restrict__ Xin,            // [MTOT,50] f32 time-major
    const float* __restrict__ W,              // [50,150] f32
    const float* __restrict__ bias,           // [2,150] f32
    float* __restrict__ xg)                   // [MTOT,XGS] f32
{
    __shared__ float xs[128][52];             // 26.6 KB, k>=50 zero
    __shared__ float Wp[52][32];              // 6.7 KB, k>=50 / col>=150 zero
    const int tid  = threadIdx.x;
    const int m0   = blockIdx.x * 128;
    const int c0   = blockIdx.y * 32;
    const int rowq = tid >> 3;
    const int colq = tid & 7;

    for (int i = tid; i < 128 * 52; i += 256) {
        int r = i / 52, k = i - r * 52;
        xs[r][k] = (k < HH) ? Xin[(size_t)m0 * HH + r * HH + k] : 0.f;
    }
    for (int i = tid; i < 52 * 32; i += 256) {
        int k = i >> 5, c = i & 31, gc = c0 + c;
        Wp[k][c] = (k < HH && gc < GG) ? W[k * GG + gc] : 0.f;
    }
    __syncthreads();

    float4 acc[4];
    #pragma unroll
    for (int j = 0; j < 4; ++j) acc[j] = make_float4(0.f, 0.f, 0.f, 0.f);

    const float* xr0 = xs[rowq * 4 + 0];
    const float* xr1 = xs[rowq * 4 + 1];
    const float* xr2 = xs[rowq * 4 + 2];
    const float* xr3 = xs[rowq * 4 + 3];
    for (int k = 0; k < 52; k += 4) {         // 13 bundles; pads contribute 0
        float4 w0 = *(const float4*)&Wp[k + 0][colq * 4];
        float4 w1 = *(const float4*)&Wp[k + 1][colq * 4];
        float4 w2 = *(const float4*)&Wp[k + 2][colq * 4];
        float4 w3 = *(const float4*)&Wp[k + 3][colq * 4];
        float4 x0 = *(const float4*)&xr0[k];
        float4 x1 = *(const float4*)&xr1[k];
        float4 x2 = *(const float4*)&xr2[k];
        float4 x3 = *(const float4*)&xr3[k];
        fma4(acc[0], x0.x, w0); fma4(acc[0], x0.y, w1);
        fma4(acc[0], x0.z, w2); fma4(acc[0], x0.w, w3);
        fma4(acc[1], x1.x, w0); fma4(acc[1], x1.y, w1);
        fma4(acc[1], x1.z, w2); fma4(acc[1], x1.w, w3);
        fma4(acc[2], x2.x, w0); fma4(acc[2], x2.y, w1);
        fma4(acc[2], x2.z, w2); fma4(acc[2], x2.w, w3);
        fma4(acc[3], x3.x, w0); fma4(acc[3], x3.y, w1);
        fma4(acc[3], x3.z, w2); fma4(acc[3], x3.w, w3);
    }
    const int cc = c0 + colq * 4;
    if (cc <= XGS - 4) {
        float4 bv = *(const float4*)&bias[cc];
        #pragma unroll
        for (int j = 0; j < 4; ++j) {
            float4 o;
            o.x = acc[j].x + bv.x; o.y = acc[j].y + bv.y;
            o.z = acc[j].z + bv.z; o.w = acc[j].w + bv.w;
            *(float4*)&xg[(size_t)(m0 + rowq * 4 + j) * XGS + cc] = o;
        }
    }
}

// ---------------- GRU recurrence: h in registers, readlane broadcast ----------------
// Proven structure (rounds 5/8/9). LDS = Ut only (40 KB) -> 2-3 blocks/CU at
// grid 512. LDS weight stream ~ 1/RPW; RPW per layer at the occupancy limit.
// `#pragma unroll 5` bounds ds_read hoisting (spill-guard, rounds 6/7 lesson).
template<int WPB, int RPW>
__global__ __launch_bounds__(WPB * 64) void gru_reg(
    const float* __restrict__ xg,             // [dn*Nbatch, XGS] f32 (includes bi)
    const float* __restrict__ U,              // [50,150] f32
    const float* __restrict__ bias,           // [2,150] f32 (br = bias+150)
    float* __restrict__ Xout,                 // [MTOT,50] f32 time-major
    int dn, int Nbatch, int ngroups)
{
    constexpr int R = WPB * RPW;              // rows per block per group
    __shared__ __align__(16) float Ut[HH][HH][4];   // [k][unit][{z,r,h,0}] 40 KB

    const int tid  = threadIdx.x;
    const int wav  = tid >> 6;
    const int lane = tid & 63;

    for (int i = tid; i < HH * HH; i += WPB * 64)
        Ut[i / HH][i - (i / HH) * HH][3] = 0.f;
    for (int i = tid; i < HH * GG; i += WPB * 64) {
        int k = i / GG, cc = i - k * GG;
        Ut[k][cc % HH][cc / HH] = U[i];       // U cols: [z|r|h] blocks of 50
    }
    __syncthreads();                          // the only block-wide barrier

    const int c  = lane;
    const int cb = (c < HH) ? c : HH - 1;     // clamped for loads (lanes 50..63)

    const float bz  = bias[GG + cb];
    const float brr = bias[GG + HH + cb];
    const float bh  = bias[GG + 2 * HH + cb];

    for (int grp = blockIdx.x; grp < ngroups; grp += gridDim.x) {
        const int row0 = grp * R + wav * RPW;
        float h[RPW];
        #pragma unroll
        for (int j = 0; j < RPW; ++j) h[j] = 0.f;
        size_t obase[RPW];
        #pragma unroll
        for (int j = 0; j < RPW; ++j) {
            int nr = row0 + j;
            obase[j] = ((size_t)((nr >> 6) * dn) * NB + (nr & 63)) * HH + cb;
        }
        const float* gb = xg + (size_t)row0 * XGS;

        float px[RPW], pr[RPW], ph[RPW];
        #pragma unroll
        for (int j = 0; j < RPW; ++j) {       // preload step 0
            const float* g = gb + (size_t)j * XGS;
            px[j] = g[cb]; pr[j] = g[HH + cb]; ph[j] = g[2 * HH + cb];
        }

        for (int s = 0; s < dn; ++s) {
            const int sn = (s + 1 < dn) ? s + 1 : s;
            float nx[RPW], nrr[RPW], nh[RPW];
            #pragma unroll
            for (int j = 0; j < RPW; ++j) {
                const float* g = gb + ((size_t)sn * Nbatch + j) * XGS;
                nx[j] = g[cb]; nrr[j] = g[HH + cb]; nh[j] = g[2 * HH + cb];
            }
            float az[RPW], ar[RPW], ah[RPW];
            #pragma unroll
            for (int j = 0; j < RPW; ++j) { az[j] = bz; ar[j] = brr; ah[j] = bh; }
            #pragma unroll 5
            for (int k = 0; k < HH; ++k) {
                float4 w = *(const float4*)&Ut[k][c < HH ? c : 0][0];
                #pragma unroll
                for (int j = 0; j < RPW; ++j) {
                    float hk = bcast(h[j], k);
                    az[j] += hk * w.x;
                    ar[j] += hk * w.y;
                    ah[j] += hk * w.z;
                }
            }
            #pragma unroll
            for (int j = 0; j < RPW; ++j) {
                float z  = sigm(px[j] + az[j]);
                float r  = sigm(pr[j] + ar[j]);
                float hh = tanh_f(ph[j] + r * ah[j]);
                float hn = z * h[j] + (1.f - z) * hh;
                h[j] = hn;
                if (c < HH) Xout[obase[j] + (size_t)s * NB * HH] = hn;
            }
            #pragma unroll
            for (int j = 0; j < RPW; ++j) { px[j] = nx[j]; pr[j] = nrr[j]; ph[j] = nh[j]; }
        }
    }
}

// ---------------- Head: split-K partial GEMM (no bias/relu here) ----------------
__global__ __launch_bounds__(256) void dense2_kernel(
    const float* __restrict__ X,              // [MTOT,50] f32 final layer (time-major)
    const float* __restrict__ W2,             // [1600,1600] f32
    float* __restrict__ part)                 // [16,64,1600] f32 partials
{
    __shared__ float fs[8][100];              // 3.2 KB
    const int tid = threadIdx.x;
    const int c  = blockIdx.x * 256 + tid;
    const int r0 = blockIdx.y * 8;
    const int kz = blockIdx.z;
    for (int i = tid; i < 8 * 100; i += 256) {
        int r = i / 100, fl = i - r * 100;
        int f = kz * 100 + fl, j = f / HH, k = f - j * HH;
        fs[r][fl] = X[((size_t)(TTT - 32 + j) * NB + (r0 + r)) * HH + k];
    }
    __syncthreads();
    if (c < 1600) {
        float a[8] = {0, 0, 0, 0, 0, 0, 0, 0};
        const float* w = W2 + (size_t)kz * 100 * 1600 + c;
        for (int fl = 0; fl < 100; ++fl) {
            float wv = w[(size_t)fl * 1600];
            #pragma unroll
            for (int r = 0; r < 8; ++r) a[r] += fs[r][fl] * wv;
        }
        #pragma unroll
        for (int r = 0; r < 8; ++r)
            part[((size_t)kz * NB + r0 + r) * 1600 + c] = a[r];
    }
}

// ---------------- Classifier: sum partials + bias + relu, then softmax ----------------
__global__ __launch_bounds__(256) void cls_kernel(
    const float* __restrict__ part,           // [16,64,1600] f32 partials
    const float* __restrict__ b2,             // [1600] f32
    const float* __restrict__ Wc,             // [1600,41] f32
    const float* __restrict__ bc,             // [41] f32
    float* __restrict__ out)                  // [64,41] f32
{
    __shared__ float hrow[1600];
    __shared__ float lg[41];
    __shared__ float red[2];
    const int b = blockIdx.x;
    const int t = threadIdx.x;
    for (int i = t; i < 1600; i += 256) {
        float s = b2[i];
        #pragma unroll 4
        for (int kz = 0; kz < 16; ++kz)
            s += part[((size_t)kz * NB + b) * 1600 + i];
        hrow[i] = s > 0.f ? s : 0.f;
    }
    __syncthreads();
    if (t < 41) {
        float acc = bc[t];
        for (int f = 0; f < 1600; ++f) acc += hrow[f] * Wc[f * 41 + t];
        lg[t] = acc;
    }
    __syncthreads();
    if (t == 0) {
        float mx = lg[0];
        for (int i = 1; i < 41; ++i) mx = fmaxf(mx, lg[i]);
        red[0] = mx;
    }
    __syncthreads();
    if (t < 41) lg[t] = expf(lg[t] - red[0]);
    __syncthreads();
    if (t == 0) {
        float sm = 0.f;
        for (int i = 0; i < 41; ++i) sm += lg[i];
        red[1] = 1.f / sm;
    }
    __syncthreads();
    if (t < 41) out[b * 41 + t] = lg[t] * red[1];
}

extern "C" void kernel_launch(void* const* d_in, const int* in_sizes, int n_in,
                              void* d_out, int out_size, void* d_ws, size_t ws_size,
                              hipStream_t stream)
{
    const float* x   = (const float*)d_in[0];    // [64,2048,128]
    const float* W0  = (const float*)d_in[1];    // [128,150]
    const float* U0  = (const float*)d_in[2];    // [50,150]
    const float* b0  = (const float*)d_in[3];    // [2,150]
    const float* Ws  = (const float*)d_in[4];    // [5,50,150]
    const float* Us  = (const float*)d_in[5];    // [5,50,150]
    const float* bs  = (const float*)d_in[6];    // [5,2,150]
    const float* W2  = (const float*)d_in[7];    // [1600,1600]
    const float* b2  = (const float*)d_in[8];    // [1600]
    const float* Wc  = (const float*)d_in[9];    // [1600,41]
    const float* bc  = (const float*)d_in[10];   // [41]

    // Round-5 proven workspace layout:
    //   xg   = region1 (MTOT*XGS, 79.7 MB); part reuses it for the head
    //   Xbuf = after xg (MTOT*HH, 26.2 MB)
    float* xg   = (float*)d_ws;
    float* Xbuf = xg + (size_t)MTOT * XGS;
    float* part = xg;

    static const int rates[6] = {32, 64, 128, 256, 512, 1024};

    // ---- layer 0: GEMM proj + gru_reg (RPW=2, round-9 config ~115 us) ----
    proj0_kernel<<<dim3(MTOT / 128, 5), 256, 0, stream>>>(x, W0, b0, xg);
    {
        int dn = TTT / rates[0], Nbatch = rates[0] * NB;   // 64, 2048
        int ngroups = Nbatch / 8;                          // R=8 for <4,2>
        int grid = ngroups < 512 ? ngroups : 512;
        gru_reg<4, 2><<<grid, 256, 0, stream>>>(xg, U0, b0, Xbuf, dn, Nbatch, ngroups);
    }

    // ---- layers 1..5: split projH (GEMM) + gru_reg (RPW at occupancy limit) ----
    for (int l = 1; l < 6; ++l) {
        const float* Wl = Ws + (size_t)(l - 1) * HH * GG;
        const float* Ul = Us + (size_t)(l - 1) * HH * GG;
        const float* bl = bs + (size_t)(l - 1) * 2 * GG;
        projH_kernel<<<dim3(MTOT / 128, 5), 256, 0, stream>>>(Xbuf, Wl, bl, xg);
        int rate = rates[l];
        int Nbatch = rate * NB;
        int dn = TTT / rate;
        if (l == 1) {                                      // Nbatch=4096: RPW=2, 512 blocks
            int ngroups = Nbatch / 8;
            int grid = ngroups < 512 ? ngroups : 512;
            gru_reg<4, 2><<<grid, 256, 0, stream>>>(xg, Ul, bl, Xbuf, dn, Nbatch, ngroups);
        } else if (l == 2) {                               // Nbatch=8192: RPW=4, 512 blocks
            int ngroups = Nbatch / 16;
            int grid = ngroups < 512 ? ngroups : 512;
            gru_reg<4, 4><<<grid, 256, 0, stream>>>(xg, Ul, bl, Xbuf, dn, Nbatch, ngroups);
        } else {                                           // Nbatch>=16384: RPW=8
            int ngroups = Nbatch / 32;
            int grid = ngroups < 512 ? ngroups : 512;
            gru_reg<4, 8><<<grid, 256, 0, stream>>>(xg, Ul, bl, Xbuf, dn, Nbatch, ngroups);
        }
    }

    // head: split-K dense2 into partials (reuses xg), reduce+relu inside cls
    dense2_kernel<<<dim3(7, 8, 16), 256, 0, stream>>>(Xbuf, W2, part);
    cls_kernel<<<NB, 256, 0, stream>>>(part, b2, Wc, bc, (float*)d_out);
}

// Round 12
// 890.668 us; speedup vs baseline: 1.3324x; 1.3324x over previous
//
#include <hip/hip_runtime.h>
#include <math.h>

// Dims (fixed by the problem)
#define HH   50          // hidden
#define GG   150         // 3H
#define XGS  152         // xg row stride (padded)
#define TTT  2048        // T
#define NB   64          // batch B
#define MTOT (TTT*NB)    // 131072 rows per layer
#define D0   128         // layer-0 input dim

static __device__ __forceinline__ float sigm(float x) {
    return 1.f / (1.f + __expf(-x));
}
static __device__ __forceinline__ float tanh_f(float x) {
    return 1.f - 2.f / (__expf(2.f * x) + 1.f);   // saturates correctly at +/-inf
}

static __device__ __forceinline__ void fma4(float4& a, float s, const float4& w) {
    a.x += s * w.x; a.y += s * w.y; a.z += s * w.z; a.w += s * w.w;
}

static __device__ __forceinline__ float bcast(float v, int k) {
    return __uint_as_float(__builtin_amdgcn_readlane(__float_as_uint(v), k));
}

// ---------------- Layer-0 input projection: Xg = X0 @ W + bi ----------------
// (proven, ~110 us)
__global__ __launch_bounds__(256) void proj0_kernel(
    const float* __restrict__ x,              // [64,2048,128] f32
    const float* __restrict__ W,              // [128,150] f32
    const float* __restrict__ bias,           // [2,150] f32 (bi = bias[0])
    float* __restrict__ xg)                   // [MTOT,XGS] f32
{
    __shared__ float xs[128][36];             // k-quarter of x, stride 36 (18.4 KB)
    __shared__ float Wp[32][32];              // k-quarter of W cols for this tile (4 KB)
    const int tid  = threadIdx.x;
    const int m0   = blockIdx.x * 128;
    const int c0   = blockIdx.y * 32;         // col-tile base: 0,32,64,96,128
    const int rowq = tid >> 3;                // 0..31
    const int colq = tid & 7;                 // 0..7

    float4 acc[4];
    #pragma unroll
    for (int j = 0; j < 4; ++j) acc[j] = make_float4(0.f, 0.f, 0.f, 0.f);

    for (int q = 0; q < 4; ++q) {             // K quarters of 32
        if (q) __syncthreads();
        for (int i = tid; i < 128 * 8; i += 256) {
            int r = i >> 3, k4 = (i & 7) * 4;
            int row = m0 + r, t = row >> 6, b = row & 63;
            *(float4*)&xs[r][k4] =
                *(const float4*)&x[((size_t)b * TTT + t) * D0 + q * 32 + k4];
        }
        for (int i = tid; i < 32 * 32; i += 256) {
            int k = i >> 5, c = i & 31, gc = c0 + c;
            Wp[k][c] = (gc < GG) ? W[(q * 32 + k) * GG + gc] : 0.f;
        }
        __syncthreads();
        const float* xr0 = xs[rowq * 4 + 0];
        const float* xr1 = xs[rowq * 4 + 1];
        const float* xr2 = xs[rowq * 4 + 2];
        const float* xr3 = xs[rowq * 4 + 3];
        for (int k = 0; k < 32; k += 4) {
            float4 w0 = *(const float4*)&Wp[k + 0][colq * 4];
            float4 w1 = *(const float4*)&Wp[k + 1][colq * 4];
            float4 w2 = *(const float4*)&Wp[k + 2][colq * 4];
            float4 w3 = *(const float4*)&Wp[k + 3][colq * 4];
            float4 x0 = *(const float4*)&xr0[k];
            float4 x1 = *(const float4*)&xr1[k];
            float4 x2 = *(const float4*)&xr2[k];
            float4 x3 = *(const float4*)&xr3[k];
            fma4(acc[0], x0.x, w0); fma4(acc[0], x0.y, w1);
            fma4(acc[0], x0.z, w2); fma4(acc[0], x0.w, w3);
            fma4(acc[1], x1.x, w0); fma4(acc[1], x1.y, w1);
            fma4(acc[1], x1.z, w2); fma4(acc[1], x1.w, w3);
            fma4(acc[2], x2.x, w0); fma4(acc[2], x2.y, w1);
            fma4(acc[2], x2.z, w2); fma4(acc[2], x2.w, w3);
            fma4(acc[3], x3.x, w0); fma4(acc[3], x3.y, w1);
            fma4(acc[3], x3.z, w2); fma4(acc[3], x3.w, w3);
        }
    }
    const int cc = c0 + colq * 4;
    if (cc <= XGS - 4) {                      // cc <= 148; cols 150/151 unread pad
        float4 bv = *(const float4*)&bias[cc];
        #pragma unroll
        for (int j = 0; j < 4; ++j) {
            float4 o;
            o.x = acc[j].x + bv.x; o.y = acc[j].y + bv.y;
            o.z = acc[j].z + bv.z; o.w = acc[j].w + bv.w;
            *(float4*)&xg[(size_t)(m0 + rowq * 4 + j) * XGS + cc] = o;
        }
    }
}

// ---------------- Layer-0 GRU: h in registers, readlane broadcast ----------------
// (unchanged from R9 -- proven; consumes xg with XGS stride)
template<int WPB, int RPW>
__global__ __launch_bounds__(WPB * 64) void gru_reg(
    const float* __restrict__ xg,             // [dn*Nbatch, XGS] f32 (includes bi)
    const float* __restrict__ U,              // [50,150] f32
    const float* __restrict__ bias,           // [2,150] f32 (br = bias+150)
    float* __restrict__ Xout,                 // [MTOT,50] f32 time-major
    int dn, int Nbatch, int ngroups)
{
    constexpr int R = WPB * RPW;              // rows per block per group
    __shared__ __align__(16) float Ut[HH][HH][4];   // [k][unit][{z,r,h,0}] 40 KB

    const int tid  = threadIdx.x;
    const int wav  = tid >> 6;
    const int lane = tid & 63;

    for (int i = tid; i < HH * HH; i += WPB * 64)
        Ut[i / HH][i - (i / HH) * HH][3] = 0.f;
    for (int i = tid; i < HH * GG; i += WPB * 64) {
        int k = i / GG, cc = i - k * GG;
        Ut[k][cc % HH][cc / HH] = U[i];       // U cols: [z|r|h] blocks of 50
    }
    __syncthreads();                          // the only block-wide barrier

    const int c  = lane;
    const int cb = (c < HH) ? c : HH - 1;     // clamped for loads (lanes 50..63)

    const float bz  = bias[GG + cb];
    const float brr = bias[GG + HH + cb];
    const float bh  = bias[GG + 2 * HH + cb];

    for (int grp = blockIdx.x; grp < ngroups; grp += gridDim.x) {
        const int row0 = grp * R + wav * RPW;
        float h[RPW];
        #pragma unroll
        for (int j = 0; j < RPW; ++j) h[j] = 0.f;
        size_t obase[RPW];
        #pragma unroll
        for (int j = 0; j < RPW; ++j) {
            int nr = row0 + j;
            obase[j] = ((size_t)((nr >> 6) * dn) * NB + (nr & 63)) * HH + cb;
        }
        const float* gb = xg + (size_t)row0 * XGS;

        float px[RPW], pr[RPW], ph[RPW];
        #pragma unroll
        for (int j = 0; j < RPW; ++j) {       // preload step 0
            const float* g = gb + (size_t)j * XGS;
            px[j] = g[cb]; pr[j] = g[HH + cb]; ph[j] = g[2 * HH + cb];
        }

        for (int s = 0; s < dn; ++s) {
            const int sn = (s + 1 < dn) ? s + 1 : s;
            float nx[RPW], nrr[RPW], nh[RPW];
            #pragma unroll
            for (int j = 0; j < RPW; ++j) {
                const float* g = gb + ((size_t)sn * Nbatch + j) * XGS;
                nx[j] = g[cb]; nrr[j] = g[HH + cb]; nh[j] = g[2 * HH + cb];
            }
            float az[RPW], ar[RPW], ah[RPW];
            #pragma unroll
            for (int j = 0; j < RPW; ++j) { az[j] = bz; ar[j] = brr; ah[j] = bh; }
            #pragma unroll 5
            for (int k = 0; k < HH; ++k) {
                float4 w = *(const float4*)&Ut[k][c < HH ? c : 0][0];
                #pragma unroll
                for (int j = 0; j < RPW; ++j) {
                    float hk = bcast(h[j], k);
                    az[j] += hk * w.x;
                    ar[j] += hk * w.y;
                    ah[j] += hk * w.z;
                }
            }
            #pragma unroll
            for (int j = 0; j < RPW; ++j) {
                float z  = sigm(px[j] + az[j]);
                float r  = sigm(pr[j] + ar[j]);
                float hh = tanh_f(ph[j] + r * ah[j]);
                float hn = z * h[j] + (1.f - z) * hh;
                h[j] = hn;
                if (c < HH) Xout[obase[j] + (size_t)s * NB * HH] = hn;
            }
            #pragma unroll
            for (int j = 0; j < RPW; ++j) { px[j] = nx[j]; pr[j] = nrr[j]; ph[j] = nh[j]; }
        }
    }
}

// ---------------- Fused proj+GRU v2: LDS-broadcast h/x, packed weights ----------------
// Replaces v_readlane (VALU->SGPR->VALU hazard, +1 instr per k per row) with
// same-address LDS float4 broadcasts (conflict-free). Weights packed:
// UWs[k][c]={Uz,Ur,Uh,Wz} (b128) + W2s[k][c]={Wr,Wh} (b64) = 60 KB. hsT/xsT
// transposed state, rows padded to R+4 floats (keeps b128 reads 16B-aligned,
// spreads the per-step transpose writes over 8 banks). LDS <= 68 KB -> 2
// blocks/CU. Per k at RPW=4: 4 LDS + 24 FMA = 28 instr (R9 readlane: 37).
// Numerics identical to R9 fused (bias-init, k ascending).
template<int WPB, int RPW>
__global__ __launch_bounds__(WPB * 64) void gru_fused2(
    const float* __restrict__ Xin,            // [dn*Nbatch, HH] f32 (prev layer)
    const float* __restrict__ W,              // [50,150] f32
    const float* __restrict__ U,              // [50,150] f32
    const float* __restrict__ bias,           // [2,150] f32
    float* __restrict__ Xout,                 // [MTOT,50] f32 time-major
    int dn, int Nbatch, int ngroups)
{
    constexpr int R  = WPB * RPW;             // rows per block per group
    constexpr int RS = R + 4;                 // padded row stride (16B-aligned)
    __shared__ __align__(16) float UWs[HH][HH][4];  // {Uz,Ur,Uh,Wz} 40 KB
    __shared__ __align__(16) float W2s[HH][HH][2];  // {Wr,Wh}       20 KB
    __shared__ __align__(16) float hsT[HH][RS];     // h state, [unit][col]
    __shared__ __align__(16) float xsT[HH][RS];     // x of current step

    const int tid  = threadIdx.x;
    const int wav  = tid >> 6;
    const int lane = tid & 63;

    for (int i = tid; i < HH * HH; i += WPB * 64) {
        int k = i / HH, cc = i - k * HH;
        const float* u = U + k * GG;
        const float* w = W + k * GG;
        UWs[k][cc][0] = u[cc];
        UWs[k][cc][1] = u[HH + cc];
        UWs[k][cc][2] = u[2 * HH + cc];
        UWs[k][cc][3] = w[cc];
        W2s[k][cc][0] = w[HH + cc];
        W2s[k][cc][1] = w[2 * HH + cc];
    }
    __syncthreads();                          // the only block-wide barrier

    const int c   = lane;
    const int cb  = (c < HH) ? c : HH - 1;
    const bool act = (c < HH);

    const float biz = bias[cb];
    const float bir = bias[HH + cb];
    const float bih = bias[2 * HH + cb];
    const float brz = bias[GG + cb];
    const float brr = bias[GG + HH + cb];
    const float brh = bias[GG + 2 * HH + cb];

    for (int grp = blockIdx.x; grp < ngroups; grp += gridDim.x) {
        const int row0 = grp * R + wav * RPW;
        float h[RPW], px[RPW];
        size_t obase[RPW];
        #pragma unroll
        for (int j = 0; j < RPW; ++j) {
            h[j] = 0.f;
            int nr = row0 + j;
            obase[j] = ((size_t)((nr >> 6) * dn) * NB + (nr & 63)) * HH + cb;
        }
        if (act) {
            #pragma unroll
            for (int j = 0; j < RPW; ++j) hsT[c][wav * RPW + j] = 0.f;
        }
        const float* gb = Xin + (size_t)row0 * HH;
        #pragma unroll
        for (int j = 0; j < RPW; ++j) px[j] = gb[(size_t)j * HH + cb];   // step 0

        for (int s = 0; s < dn; ++s) {
            // publish this step's x (transposed; wave-owned columns, no barrier)
            if (act) {
                #pragma unroll
                for (int j = 0; j < RPW; ++j) xsT[c][wav * RPW + j] = px[j];
            }
            // prefetch next step's x (lands during the k-loop)
            const int sn = (s + 1 < dn) ? s + 1 : s;
            float nx[RPW];
            #pragma unroll
            for (int j = 0; j < RPW; ++j)
                nx[j] = gb[((size_t)sn * Nbatch + j) * HH + cb];

            float gz[RPW], gr[RPW], gh[RPW], az[RPW], ar[RPW], ah[RPW];
            #pragma unroll
            for (int j = 0; j < RPW; ++j) {
                gz[j] = biz; gr[j] = bir; gh[j] = bih;
                az[j] = brz; ar[j] = brr; ah[j] = brh;
            }
            #pragma unroll 5
            for (int k = 0; k < HH; ++k) {
                float4 uw = *(const float4*)&UWs[k][cb][0];
                float2 w2 = *(const float2*)&W2s[k][cb][0];
                float hv[RPW], xv[RPW];
                if constexpr (RPW == 4) {
                    float4 t  = *(const float4*)&hsT[k][wav * RPW];
                    hv[0] = t.x; hv[1] = t.y; hv[2] = t.z; hv[3] = t.w;
                    float4 u2 = *(const float4*)&xsT[k][wav * RPW];
                    xv[0] = u2.x; xv[1] = u2.y; xv[2] = u2.z; xv[3] = u2.w;
                } else {
                    float2 t  = *(const float2*)&hsT[k][wav * RPW];
                    hv[0] = t.x; hv[1] = t.y;
                    float2 u2 = *(const float2*)&xsT[k][wav * RPW];
                    xv[0] = u2.x; xv[1] = u2.y;
                }
                #pragma unroll
                for (int j = 0; j < RPW; ++j) {
                    az[j] += hv[j] * uw.x;
                    ar[j] += hv[j] * uw.y;
                    ah[j] += hv[j] * uw.z;
                    gz[j] += xv[j] * uw.w;
                    gr[j] += xv[j] * w2.x;
                    gh[j] += xv[j] * w2.y;
                }
            }
            #pragma unroll
            for (int j = 0; j < RPW; ++j) {
                float z  = sigm(gz[j] + az[j]);
                float r  = sigm(gr[j] + ar[j]);
                float hh = tanh_f(gh[j] + r * ah[j]);
                float hn = z * h[j] + (1.f - z) * hh;
                h[j] = hn;
                if (act) {
                    hsT[c][wav * RPW + j] = hn;
                    Xout[obase[j] + (size_t)s * NB * HH] = hn;
                }
            }
            #pragma unroll
            for (int j = 0; j < RPW; ++j) px[j] = nx[j];
        }
    }
}

// ---------------- Head: split-K partial GEMM (no bias/relu here) ----------------
__global__ __launch_bounds__(256) void dense2_kernel(
    const float* __restrict__ X,              // [MTOT,50] f32 final layer (time-major)
    const float* __restrict__ W2,             // [1600,1600] f32
    float* __restrict__ part)                 // [16,64,1600] f32 partials
{
    __shared__ float fs[8][100];              // 3.2 KB
    const int tid = threadIdx.x;
    const int c  = blockIdx.x * 256 + tid;
    const int r0 = blockIdx.y * 8;
    const int kz = blockIdx.z;
    for (int i = tid; i < 8 * 100; i += 256) {
        int r = i / 100, fl = i - r * 100;
        int f = kz * 100 + fl, j = f / HH, k = f - j * HH;
        fs[r][fl] = X[((size_t)(TTT - 32 + j) * NB + (r0 + r)) * HH + k];
    }
    __syncthreads();
    if (c < 1600) {
        float a[8] = {0, 0, 0, 0, 0, 0, 0, 0};
        const float* w = W2 + (size_t)kz * 100 * 1600 + c;
        for (int fl = 0; fl < 100; ++fl) {
            float wv = w[(size_t)fl * 1600];
            #pragma unroll
            for (int r = 0; r < 8; ++r) a[r] += fs[r][fl] * wv;
        }
        #pragma unroll
        for (int r = 0; r < 8; ++r)
            part[((size_t)kz * NB + r0 + r) * 1600 + c] = a[r];
    }
}

// ---------------- Classifier: sum partials + bias + relu, then softmax ----------------
__global__ __launch_bounds__(256) void cls_kernel(
    const float* __restrict__ part,           // [16,64,1600] f32 partials
    const float* __restrict__ b2,             // [1600] f32
    const float* __restrict__ Wc,             // [1600,41] f32
    const float* __restrict__ bc,             // [41] f32
    float* __restrict__ out)                  // [64,41] f32
{
    __shared__ float hrow[1600];
    __shared__ float lg[41];
    __shared__ float red[2];
    const int b = blockIdx.x;
    const int t = threadIdx.x;
    for (int i = t; i < 1600; i += 256) {
        float s = b2[i];
        #pragma unroll 4
        for (int kz = 0; kz < 16; ++kz)
            s += part[((size_t)kz * NB + b) * 1600 + i];
        hrow[i] = s > 0.f ? s : 0.f;
    }
    __syncthreads();
    if (t < 41) {
        float acc = bc[t];
        for (int f = 0; f < 1600; ++f) acc += hrow[f] * Wc[f * 41 + t];
        lg[t] = acc;
    }
    __syncthreads();
    if (t == 0) {
        float mx = lg[0];
        for (int i = 1; i < 41; ++i) mx = fmaxf(mx, lg[i]);
        red[0] = mx;
    }
    __syncthreads();
    if (t < 41) lg[t] = expf(lg[t] - red[0]);
    __syncthreads();
    if (t == 0) {
        float sm = 0.f;
        for (int i = 0; i < 41; ++i) sm += lg[i];
        red[1] = 1.f / sm;
    }
    __syncthreads();
    if (t < 41) out[b * 41 + t] = lg[t] * red[1];
}

extern "C" void kernel_launch(void* const* d_in, const int* in_sizes, int n_in,
                              void* d_out, int out_size, void* d_ws, size_t ws_size,
                              hipStream_t stream)
{
    const float* x   = (const float*)d_in[0];    // [64,2048,128]
    const float* W0  = (const float*)d_in[1];    // [128,150]
    const float* U0  = (const float*)d_in[2];    // [50,150]
    const float* b0  = (const float*)d_in[3];    // [2,150]
    const float* Ws  = (const float*)d_in[4];    // [5,50,150]
    const float* Us  = (const float*)d_in[5];    // [5,50,150]
    const float* bs  = (const float*)d_in[6];    // [5,2,150]
    const float* W2  = (const float*)d_in[7];    // [1600,1600]
    const float* b2  = (const float*)d_in[8];    // [1600]
    const float* Wc  = (const float*)d_in[9];    // [1600,41]
    const float* bc  = (const float*)d_in[10];   // [41]

    // R9-proven workspace layout:
    //   region1 = MTOT*XGS floats: xg (layer 0) -> bufB (layers 1..5)
    //             part at region1 + MTOT*HH (disjoint from bufB)
    //   bufA    = MTOT*HH floats after region1
    float* region1 = (float*)d_ws;
    float* xg   = region1;
    float* bufB = region1;
    float* part = region1 + (size_t)MTOT * HH;
    float* bufA = region1 + (size_t)MTOT * XGS;

    static const int rates[6] = {32, 64, 128, 256, 512, 1024};

    // ---- layer 0: GEMM proj + gru_reg (R9 config) ----
    proj0_kernel<<<dim3(MTOT / 128, 5), 256, 0, stream>>>(x, W0, b0, xg);
    {
        int dn = TTT / rates[0], Nbatch = rates[0] * NB;   // 64, 2048
        int ngroups = Nbatch / 8;                          // R=8 for <4,2>
        int grid = ngroups < 512 ? ngroups : 512;
        gru_reg<4, 2><<<grid, 256, 0, stream>>>(xg, U0, b0, bufA, dn, Nbatch, ngroups);
    }

    // ---- layers 1..5: fused2 (LDS-broadcast), ping-pong bufA <-> bufB ----
    const float* cur = bufA;
    for (int l = 1; l < 6; ++l) {
        const float* Wl = Ws + (size_t)(l - 1) * HH * GG;
        const float* Ul = Us + (size_t)(l - 1) * HH * GG;
        const float* bl = bs + (size_t)(l - 1) * 2 * GG;
        int rate = rates[l];
        int Nbatch = rate * NB;
        int dn = TTT / rate;
        float* dst = (cur == bufA) ? bufB : bufA;
        if (l == 1) {                                      // Nbatch=4096: RPW=2, R=8
            int ngroups = Nbatch / 8;
            int grid = ngroups < 512 ? ngroups : 512;
            gru_fused2<4, 2><<<grid, 256, 0, stream>>>(cur, Wl, Ul, bl, dst, dn, Nbatch, ngroups);
        } else {                                           // RPW=4, R=16
            int ngroups = Nbatch / 16;
            int grid = ngroups < 512 ? ngroups : 512;
            gru_fused2<4, 4><<<grid, 256, 0, stream>>>(cur, Wl, Ul, bl, dst, dn, Nbatch, ngroups);
        }
        cur = dst;
    }
    // ping-pong A->B->A->B->A->B: final cur = bufB (disjoint from part)

    // head: split-K dense2 into partials, reduce+relu inside cls
    dense2_kernel<<<dim3(7, 8, 16), 256, 0, stream>>>(cur, W2, part);
    cls_kernel<<<NB, 256, 0, stream>>>(part, b2, Wc, bc, (float*)d_out);
}